// Round 1
// 283.627 us; speedup vs baseline: 1.1854x; 1.1854x over previous
//
#include <hip/hip_runtime.h>
#include <hip/hip_fp16.h>
#include <cmath>

#define CAPB 64    // padded bucket capacity; deg~Poisson(16), P(>64)~1e-21; overflow list for safety
#define CAP0 192   // max staged degree in k_fused1 (bucket + appended overflow)
#define CAPF 88    // staged edge capacity in k_fused0 (bucket + overflow + pad-to-4)
#define WA   92    // s_wa per-head stride in halfwords (even, bank-spreading)
#define G0_ROWS 64
#define G0_PAD 68

typedef _Float16 h2v __attribute__((ext_vector_type(2)));

__device__ __forceinline__ float dot2a(unsigned f, unsigned w, float acc) {
  return __builtin_amdgcn_fdot2(__builtin_bit_cast(h2v, f),
                                __builtin_bit_cast(h2v, w), acc, false);
}
__device__ __forceinline__ unsigned pkh2(float lo, float hi) {
  return (unsigned)__half_as_ushort(__float2half_rn(lo)) |
         ((unsigned)__half_as_ushort(__float2half_rn(hi)) << 16);
}

// ---------------- merged kernel: gemm blocks OR scatter blocks (disjoint) ----------
// First ngemm blocks: GEMM0 tile only. Remaining blocks: edge scatter only.
// Block ngemm additionally packs W1 into fp16 half2-pair layout W1ct[c][k2] for fused0.
__global__ void k_gemm0_scatter(const float* __restrict__ x, const float* __restrict__ W0,
                                const float* __restrict__ al, const float* __restrict__ ar,
                                const int* __restrict__ dst, const int* __restrict__ src,
                                const float* __restrict__ W1, unsigned* __restrict__ W1ct,
                                unsigned short* __restrict__ f0h, float* __restrict__ el,
                                float* __restrict__ er, int* __restrict__ cnt,
                                int* __restrict__ ovf_cnt, int* __restrict__ bpad,
                                int* __restrict__ ovf, int N, int E, int ngemm) {
  __shared__ float s_x[128 * G0_PAD];
  int t = threadIdx.x;

  if (blockIdx.x >= ngemm) {
    // ---- W1 fp16 pack (one block only): W1ct[c*128+k2] = {W1[2k2][c], W1[2k2+1][c]} ----
    if (blockIdx.x == ngemm) {
      for (int idx = t; idx < 4096; idx += 256) {
        int c = idx >> 7, k2 = idx & 127;
        float lo = W1[(size_t)(2 * k2) * 32 + c];
        float hi = W1[(size_t)(2 * k2 + 1) * 32 + c];
        W1ct[idx] = pkh2(lo, hi);
      }
    }
    // ---- scatter share (grid-stride over scatter blocks only) ----
    int nscat = gridDim.x - ngemm;
    for (int e = (blockIdx.x - ngemm) * blockDim.x + t; e < E; e += nscat * blockDim.x) {
      int d = dst[e];
      int pos = atomicAdd(&cnt[d], 1);
      if (pos < CAPB) bpad[(size_t)d * CAPB + pos] = src[e];
      else { int op = atomicAdd(ovf_cnt, 1); ovf[op] = e; }
    }
    return;
  }

  // ---- gemm0 tile ----
  int w = t >> 6, l = t & 63;
  int row0 = blockIdx.x * G0_ROWS;
  {
    int row = row0 + l; if (row >= N) row = N - 1;
    const float* xp = x + (size_t)row * 128 + w * 32;
#pragma unroll
    for (int j = 0; j < 8; ++j) {
      float4 v = *(const float4*)(xp + 4 * j);
      int k = w * 32 + 4 * j;
      s_x[(k + 0) * G0_PAD + l] = v.x;
      s_x[(k + 1) * G0_PAD + l] = v.y;
      s_x[(k + 2) * G0_PAD + l] = v.z;
      s_x[(k + 3) * G0_PAD + l] = v.w;
    }
  }
  __syncthreads();

  float4 acc[16];
#pragma unroll
  for (int r = 0; r < 16; ++r) acc[r] = make_float4(0.f, 0.f, 0.f, 0.f);

  const float* wp = W0 + 4 * l;
  int rbase = w * 16;
  for (int k = 0; k < 128; ++k) {
    float4 w4 = *(const float4*)(wp + (size_t)k * 256);
    const float* xk = &s_x[k * G0_PAD + rbase];
    float xv[16];
    *(float4*)&xv[0]  = *(const float4*)(xk);
    *(float4*)&xv[4]  = *(const float4*)(xk + 4);
    *(float4*)&xv[8]  = *(const float4*)(xk + 8);
    *(float4*)&xv[12] = *(const float4*)(xk + 12);
#pragma unroll
    for (int r = 0; r < 16; ++r) {
      acc[r].x = fmaf(xv[r], w4.x, acc[r].x);
      acc[r].y = fmaf(xv[r], w4.y, acc[r].y);
      acc[r].z = fmaf(xv[r], w4.z, acc[r].z);
      acc[r].w = fmaf(xv[r], w4.w, acc[r].w);
    }
  }

  int hh = l >> 3;
  float4 al4 = *(const float4*)(al + 4 * l);
  float4 ar4 = *(const float4*)(ar + 4 * l);
#pragma unroll
  for (int r = 0; r < 16; ++r) {
    int row = row0 + rbase + r;
    float4 f = acc[r];
    if (row < N) {
      ushort4 h4;
      h4.x = __half_as_ushort(__float2half_rn(f.x));
      h4.y = __half_as_ushort(__float2half_rn(f.y));
      h4.z = __half_as_ushort(__float2half_rn(f.z));
      h4.w = __half_as_ushort(__float2half_rn(f.w));
      *(ushort4*)(f0h + (size_t)row * 256 + 4 * l) = h4;
    }
    float pl = fmaf(f.x, al4.x, fmaf(f.y, al4.y, fmaf(f.z, al4.z, f.w * al4.w)));
    float pr = fmaf(f.x, ar4.x, fmaf(f.y, ar4.y, fmaf(f.z, ar4.z, f.w * ar4.w)));
#pragma unroll
    for (int off = 4; off >= 1; off >>= 1) {
      pl += __shfl_xor(pl, off, 64);
      pr += __shfl_xor(pr, off, 64);
    }
    if ((l & 7) == 0 && row < N) {
      el[row * 8 + hh] = pl;
      er[row * 8 + hh] = pr;
    }
  }
}

// ---------------- fused edge kernel layer 0 + layer-1 projection -------------------
// One WAVE per node (4 nodes / 256-thread block). All per-node LDS is wave-private:
// no per-node barriers. Single barrier per block stages packed-fp16 W1 into LDS.
// Gather inner loop: v_perm pairs two edges' fp16 values, v_dot2_f32_f16 accumulates
// with the fp16 softmax-weight pair read as one dword from LDS.
__global__ void k_fused0(const float* __restrict__ el, const float* __restrict__ er,
                         const unsigned short* __restrict__ f0h, const int* __restrict__ cnt,
                         const int* __restrict__ ovf_cnt, const int* __restrict__ bpad,
                         const int* __restrict__ ovf, const int* __restrict__ dstp,
                         const int* __restrict__ src, const float* __restrict__ b0,
                         const unsigned* __restrict__ W1ct, const float* __restrict__ al1,
                         const float* __restrict__ ar1, float* __restrict__ f1,
                         float* __restrict__ el1, float* __restrict__ er1, int N) {
  __shared__ unsigned s_w1[32 * 132];          // 16896 B, W1 half2-pairs [c][k2], stride 132
  __shared__ unsigned short s_wa[4][8 * WA];   //  5888 B, fp16 softmax weights per node
  __shared__ int s_s[4][CAPF];                 //  1408 B, staged src ids per node
  __shared__ unsigned s_h2[4][128];            //  2048 B, fp16-packed h row per node

  const int t = threadIdx.x;
  // ---- stage packed W1 into LDS (pad stride 132 for bank spread) ----
  for (int base = t * 4; base < 4096; base += 1024) {
    uint4 v = *(const uint4*)&W1ct[base];
    int c = base >> 7, k2 = base & 127;
    *(uint4*)&s_w1[c * 132 + k2] = v;
  }
  __syncthreads();

  const int w = __builtin_amdgcn_readfirstlane(t >> 6);
  const int l = t & 63;
  const int n = blockIdx.x * 4 + w;
  if (n >= N) return;

  int* sS = s_s[w];
  unsigned short* sWA = s_wa[w];

  const int sub = l & 31, half = l >> 5, hh = sub >> 2;
  // per-wave constant preloads (issue early, consumed late)
  float4 b0a = ((const float4*)(b0 + 8 * sub))[0];
  float4 b0b = ((const float4*)(b0 + 8 * sub))[1];
  float al1c = al1[sub], ar1c = ar1[sub];

  // ---- stage src ids (bucket <= 64 -> one step) ----
  int cn = cnt[n];
  int degb = cn < CAPB ? cn : CAPB;
  if (l < degb) sS[l] = bpad[(size_t)n * CAPB + l];
  int deg = degb;
  int ovl = ovf_cnt[0];
  if (ovl) {                                   // never in practice
    int d = degb;
    if (l == 0) {
      for (int j = 0; j < ovl && d < 84; ++j) {
        int e = ovf[j];
        if (dstp[e] == n) sS[d++] = src[e];
      }
    }
    deg = __shfl(d, 0, 64);
  }

  // ---- scores: single pass, no max subtraction (|v| ~ O(1), exp fp32-safe),
  //      unnormalized exp stored fp16; normalization deferred to accumulator scale ----
  float er_h = er[n * 8 + (l & 7)];
  float psum = 0.f;
  for (int e = l >> 3; e < deg; e += 8) {      // lane = e*8 + h: el reads coalesced 32B
    int sidx = sS[e];
    float v = el[sidx * 8 + (l & 7)] + er_h;
    v = v >= 0.f ? v : 0.2f * v;
    float a = __expf(v);
    sWA[(l & 7) * WA + e] = __half_as_ushort(__float2half_rn(a));
    psum += a;
  }
  psum += __shfl_xor(psum, 8, 64);
  psum += __shfl_xor(psum, 16, 64);
  psum += __shfl_xor(psum, 32, 64);
  float rs = psum > 0.f ? __builtin_amdgcn_rcpf(psum) : 0.f;   // deg==0 -> scale 0

  // ---- pad edge count to multiple of 4: copy src[0] with zero weight ----
  int degp = (deg + 3) & ~3;
  if (l < degp - deg) sS[deg + l] = sS[0];
  { int pe = deg + (l >> 3); if (pe < degp) sWA[(l & 7) * WA + pe] = 0; }

  // ---- gather: 4 edges/iter; lanes<32 take e,e+1; lanes>=32 take e+2,e+3.
  //      lane covers elems 8*sub..8*sub+7 (head hh) via one b128 fp16 load/edge ----
  float a0 = 0.f, a1 = 0.f, a2 = 0.f, a3 = 0.f, a4 = 0.f, a5 = 0.f, a6 = 0.f, a7 = 0.f;
  if (degp > 0) {
    int2 sp = *(const int2*)&sS[2 * half];
    uint4 A = ((const uint4*)(f0h + (size_t)sp.x * 256))[sub];
    uint4 B = ((const uint4*)(f0h + (size_t)sp.y * 256))[sub];
    for (int i = 0;;) {
      int in = i + 4;
      uint4 A2, B2;
      if (in < degp) {                          // uniform branch: prefetch next 4 edges
        int2 s2 = *(const int2*)&sS[in + 2 * half];
        A2 = ((const uint4*)(f0h + (size_t)s2.x * 256))[sub];
        B2 = ((const uint4*)(f0h + (size_t)s2.y * 256))[sub];
      }
      unsigned wp = *(const unsigned*)&sWA[hh * WA + i + 2 * half];  // {a_e0,a_e1} fp16x2
      unsigned lo, hi;
      lo = __builtin_amdgcn_perm(A.x, B.x, 0x01000504u);   // {A.h0, B.h0}
      hi = __builtin_amdgcn_perm(A.x, B.x, 0x03020706u);   // {A.h1, B.h1}
      a0 = dot2a(lo, wp, a0); a1 = dot2a(hi, wp, a1);
      lo = __builtin_amdgcn_perm(A.y, B.y, 0x01000504u);
      hi = __builtin_amdgcn_perm(A.y, B.y, 0x03020706u);
      a2 = dot2a(lo, wp, a2); a3 = dot2a(hi, wp, a3);
      lo = __builtin_amdgcn_perm(A.z, B.z, 0x01000504u);
      hi = __builtin_amdgcn_perm(A.z, B.z, 0x03020706u);
      a4 = dot2a(lo, wp, a4); a5 = dot2a(hi, wp, a5);
      lo = __builtin_amdgcn_perm(A.w, B.w, 0x01000504u);
      hi = __builtin_amdgcn_perm(A.w, B.w, 0x03020706u);
      a6 = dot2a(lo, wp, a6); a7 = dot2a(hi, wp, a7);
      if (in >= degp) break;
      i = in; A = A2; B = B2;
    }
  }
  // fold the two edge-subset halves
  a0 += __shfl_xor(a0, 32, 64); a1 += __shfl_xor(a1, 32, 64);
  a2 += __shfl_xor(a2, 32, 64); a3 += __shfl_xor(a3, 32, 64);
  a4 += __shfl_xor(a4, 32, 64); a5 += __shfl_xor(a5, 32, 64);
  a6 += __shfl_xor(a6, 32, 64); a7 += __shfl_xor(a7, 32, 64);

  // ---- normalize + bias + ELU, pack h row to fp16 pairs in LDS ----
  float sc = __shfl(rs, hh, 64);
  float o0 = fmaf(a0, sc, b0a.x), o1 = fmaf(a1, sc, b0a.y);
  float o2 = fmaf(a2, sc, b0a.z), o3 = fmaf(a3, sc, b0a.w);
  float o4 = fmaf(a4, sc, b0b.x), o5 = fmaf(a5, sc, b0b.y);
  float o6 = fmaf(a6, sc, b0b.z), o7 = fmaf(a7, sc, b0b.w);
  o0 = o0 > 0.f ? o0 : expm1f(o0);  o1 = o1 > 0.f ? o1 : expm1f(o1);
  o2 = o2 > 0.f ? o2 : expm1f(o2);  o3 = o3 > 0.f ? o3 : expm1f(o3);
  o4 = o4 > 0.f ? o4 : expm1f(o4);  o5 = o5 > 0.f ? o5 : expm1f(o5);
  o6 = o6 > 0.f ? o6 : expm1f(o6);  o7 = o7 > 0.f ? o7 : expm1f(o7);
  if (half == 0) {
    uint4 hp;
    hp.x = pkh2(o0, o1); hp.y = pkh2(o2, o3);
    hp.z = pkh2(o4, o5); hp.w = pkh2(o6, o7);
    *(uint4*)&s_h2[w][4 * sub] = hp;
  }
  asm volatile("s_waitcnt lgkmcnt(0)" ::: "memory");  // h-row visible wave-wide

  // ---- epilogue: f1 = h @ W1 via fp16 dot2 from LDS; el1/er1 dots ----
  const unsigned* wrow = &s_w1[sub * 132 + half * 64];
  const unsigned* hrow = &s_h2[w][half * 64];
  float p = 0.f;
#pragma unroll
  for (int j = 0; j < 64; j += 4) {
    uint4 wv = *(const uint4*)&wrow[j];
    uint4 hv = *(const uint4*)&hrow[j];
    p = dot2a(hv.x, wv.x, p);
    p = dot2a(hv.y, wv.y, p);
    p = dot2a(hv.z, wv.z, p);
    p = dot2a(hv.w, wv.w, p);
  }
  p += __shfl_xor(p, 32, 64);                  // fold k-halves -> f1[c], c = sub
  float pl = p * al1c, pr = p * ar1c;
#pragma unroll
  for (int off = 16; off >= 1; off >>= 1) {
    pl += __shfl_xor(pl, off, 64);
    pr += __shfl_xor(pr, off, 64);
  }
  if (half == 0) f1[(size_t)n * 32 + sub] = p;
  if (l == 0) { el1[n] = pl; er1[n] = pr; }
}

// ---------------- fused edge kernel layer 1 (H=1, D=32, fp32 f1) ----------------
__global__ void k_fused1(const float* __restrict__ el, const float* __restrict__ er,
                         const float* __restrict__ f1, const int* __restrict__ cnt,
                         const int* __restrict__ ovf_cnt, const int* __restrict__ bpad,
                         const int* __restrict__ ovf, const int* __restrict__ dstp,
                         const int* __restrict__ src, const float* __restrict__ b1,
                         float* __restrict__ h1, int N) {
  __shared__ float s_w[4][CAP0];
  __shared__ int s_s[4][CAP0];
  int g = threadIdx.x >> 6;
  int lane = threadIdx.x & 63;
  int n = blockIdx.x * 4 + g;
  int nn = n < N ? n : N - 1;
  int cn = cnt[nn];
  int degb = cn < CAPB ? cn : CAPB;
  float er_n = er[nn];

  for (int i = lane; i < degb; i += 64)
    s_s[g][i] = bpad[(size_t)nn * CAPB + i];
  int deg = degb;
  {
    int ovl = ovf_cnt[0];
    if (ovl) {                            // never in practice
      if (lane == 0) {
        int d = degb;
        for (int j = 0; j < ovl && d < CAP0; ++j) {
          int e = ovf[j];
          if (dstp[e] == nn) s_s[g][d++] = src[e];
        }
        s_w[g][0] = __int_as_float(d);    // stash
      }
      deg = __float_as_int(__shfl(s_w[g][0], 0, 64));
    }
  }

  float m = -INFINITY;
  for (int i = lane; i < deg; i += 64) {
    float v = el[s_s[g][i]] + er_n;
    v = v >= 0.f ? v : 0.2f * v;
    s_w[g][i] = v;
    m = fmaxf(m, v);
  }
#pragma unroll
  for (int off = 32; off >= 1; off >>= 1) m = fmaxf(m, __shfl_xor(m, off, 64));
  float sum = 0.f;
  for (int i = lane; i < deg; i += 64) {
    float a = expf(s_w[g][i] - m);
    s_w[g][i] = a;
    sum += a;
  }
#pragma unroll
  for (int off = 32; off >= 1; off >>= 1) sum += __shfl_xor(sum, off, 64);
  for (int i = lane; i < deg; i += 64) s_w[g][i] /= sum;

  int es = lane >> 3, q = lane & 7;
  float4 a4 = make_float4(0.f, 0.f, 0.f, 0.f);
  int i = es;
  for (; i + 8 < deg; i += 16) {           // 2 rows in flight
    float a = s_w[g][i];
    float b = s_w[g][i + 8];
    float4 v0 = ((const float4*)(f1 + (size_t)s_s[g][i] * 32))[q];
    float4 v1 = ((const float4*)(f1 + (size_t)s_s[g][i + 8] * 32))[q];
    a4.x = fmaf(a, v0.x, a4.x); a4.y = fmaf(a, v0.y, a4.y);
    a4.z = fmaf(a, v0.z, a4.z); a4.w = fmaf(a, v0.w, a4.w);
    a4.x = fmaf(b, v1.x, a4.x); a4.y = fmaf(b, v1.y, a4.y);
    a4.z = fmaf(b, v1.z, a4.z); a4.w = fmaf(b, v1.w, a4.w);
  }
  for (; i < deg; i += 8) {
    float a = s_w[g][i];
    float4 v = ((const float4*)(f1 + (size_t)s_s[g][i] * 32))[q];
    a4.x = fmaf(a, v.x, a4.x); a4.y = fmaf(a, v.y, a4.y);
    a4.z = fmaf(a, v.z, a4.z); a4.w = fmaf(a, v.w, a4.w);
  }
#pragma unroll
  for (int off = 8; off <= 32; off <<= 1) {
    a4.x += __shfl_xor(a4.x, off, 64);
    a4.y += __shfl_xor(a4.y, off, 64);
    a4.z += __shfl_xor(a4.z, off, 64);
    a4.w += __shfl_xor(a4.w, off, 64);
  }
  if (lane < 8 && n < N) {
    float4 b = *(const float4*)(b1 + lane * 4);
    a4.x += b.x; a4.y += b.y; a4.z += b.z; a4.w += b.w;
    ((float4*)(h1 + (size_t)n * 32))[lane] = a4;
  }
}

// ---------------- predictor (f64 acc — negligible cost, keeps margin) ----------------
__global__ void k_pred(const float* __restrict__ h1, const float* __restrict__ P1,
                       const float* __restrict__ pb1, const float* __restrict__ P2,
                       const float* __restrict__ pb2, const float* __restrict__ P3,
                       const float* __restrict__ pb3, float* __restrict__ out,
                       int num_edge, int total) {
  int t = threadIdx.x;
  int lane = t & 31, grp = t >> 5;
  int k = blockIdx.x * 8 + grp;
  int kk = k < total ? k : 0;
  float z;
  if (kk < num_edge) {
    z = h1[(size_t)kk * 32 + lane] * h1[(size_t)(kk + num_edge) * 32 + lane];
  } else {
    int i = kk - num_edge;
    z = h1[(size_t)(i % num_edge) * 32 + lane] * h1[(size_t)(2 * num_edge + i) * 32 + lane];
  }
  double a1 = 0;
#pragma unroll
  for (int d = 0; d < 32; ++d)
    a1 += (double)__shfl(z, d, 32) * (double)P1[d * 32 + lane];
  float t1 = (float)(a1 + (double)pb1[lane]);
  t1 = t1 > 0.f ? t1 : 0.f;
  double a2 = 0;
#pragma unroll
  for (int d = 0; d < 32; ++d)
    a2 += (double)__shfl(t1, d, 32) * (double)P2[d * 32 + lane];
  float t2 = (float)(a2 + (double)pb2[lane]);
  t2 = t2 > 0.f ? t2 : 0.f;
  double a3 = (double)t2 * (double)P3[lane];
#pragma unroll
  for (int off = 16; off >= 1; off >>= 1) a3 += __shfl_xor(a3, off, 64);
  if (lane == 0 && k < total) out[k] = (float)(a3 + (double)pb3[0]);
}

extern "C" void kernel_launch(void* const* d_in, const int* in_sizes, int n_in,
                              void* d_out, int out_size, void* d_ws, size_t ws_size,
                              hipStream_t stream) {
  const float* x   = (const float*)d_in[0];
  const int*   src = (const int*)d_in[1];
  const int*   dst = (const int*)d_in[2];
  const float* W0  = (const float*)d_in[4];
  const float* al0 = (const float*)d_in[5];
  const float* ar0 = (const float*)d_in[6];
  const float* b0  = (const float*)d_in[7];
  const float* W1  = (const float*)d_in[8];
  const float* al1 = (const float*)d_in[9];
  const float* ar1 = (const float*)d_in[10];
  const float* b1  = (const float*)d_in[11];
  const float* P1  = (const float*)d_in[12];
  const float* pb1 = (const float*)d_in[13];
  const float* P2  = (const float*)d_in[14];
  const float* pb2 = (const float*)d_in[15];
  const float* P3  = (const float*)d_in[16];
  const float* pb3 = (const float*)d_in[17];

  int N = in_sizes[0] / 128;
  int E = in_sizes[1];
  int num_edge = N - out_size;   // N=(2+r)*ne, out=(1+r)*ne

  size_t off = 0;
  auto alloc = [&](size_t bytes) -> void* {
    void* p = (char*)d_ws + off;
    off += (bytes + 255) & ~(size_t)255;
    return p;
  };
  unsigned short* f0h = (unsigned short*)alloc((size_t)N * 256 * 2);   // fp16 gather table
  float* f1   = (float*)alloc((size_t)N * 32 * 4);
  float* h1   = (float*)alloc((size_t)N * 32 * 4);
  float* el   = (float*)alloc((size_t)N * 8 * 4);
  float* er   = (float*)alloc((size_t)N * 8 * 4);
  float* el1  = (float*)alloc((size_t)N * 4);
  float* er1  = (float*)alloc((size_t)N * 4);
  int*   cnt  = (int*)alloc((size_t)(N + 1) * 4);   // [N] = overflow counter
  int*   bpad = (int*)alloc((size_t)N * CAPB * 4);
  int*   ovf  = (int*)alloc((size_t)E * 4);
  unsigned* W1ct = (unsigned*)alloc(4096 * 4);      // packed fp16 W1 [32][128] half2-pairs
  if (off > ws_size) return;
  int* ovf_cnt = cnt + N;

  int ngemm = (N + G0_ROWS - 1) / G0_ROWS;    // 782
  hipMemsetAsync(cnt, 0, (size_t)(N + 1) * 4, stream);
  k_gemm0_scatter<<<1792, 256, 0, stream>>>(x, W0, al0, ar0, dst, src, W1, W1ct,
                                            f0h, el, er, cnt, ovf_cnt, bpad, ovf,
                                            N, E, ngemm);
  k_fused0<<<(N + 3) / 4, 256, 0, stream>>>(el, er, f0h, cnt, ovf_cnt, bpad, ovf, dst,
                                            src, b0, W1ct, al1, ar1, f1, el1, er1, N);
  k_fused1<<<(N + 3) / 4, 256, 0, stream>>>(el1, er1, f1, cnt, ovf_cnt, bpad, ovf, dst,
                                            src, b1, h1, N);
  k_pred<<<(out_size + 7) / 8, 256, 0, stream>>>(h1, P1, pb1, P2, pb2, P3, pb3,
                                                 (float*)d_out, num_edge, out_size);
}